// Round 1
// baseline (5459.358 us; speedup 1.0000x reference)
//
#include <hip/hip_runtime.h>

constexpr int N_USERS = 50000;
constexpr int N_ENT   = 100000;
constexpr int N_NODES = N_USERS + N_ENT;   // 150000
constexpr int N_EDGES = 2400000;
constexpr int OUT_D   = 176;               // 64 + 64 + 32 + 16

// ---------------------------------------------------------------------------
// Write initial x (concat of user/entity embeddings) into out columns [0:64)
// ---------------------------------------------------------------------------
__global__ __launch_bounds__(256) void init_x_kernel(const float* __restrict__ ue,
                                                     const float* __restrict__ ee,
                                                     float* __restrict__ out) {
    int tid = blockIdx.x * 256 + threadIdx.x;    // over N_NODES * 16 float4s
    int n = tid >> 4, q = tid & 15;
    const float* src = (n < N_USERS) ? ue + (size_t)n * 64
                                     : ee + (size_t)(n - N_USERS) * 64;
    float4 v = *(const float4*)(src + q * 4);
    *(float4*)(out + (size_t)n * OUT_D + q * 4) = v;
}

// ---------------------------------------------------------------------------
// side[row] += edge_val * x[col]   (x read from out slab at column cin)
// One thread handles one (edge, 4-dim) chunk: float4 gather + 4 atomicAdds.
// LDQ = log2(din/4)
// ---------------------------------------------------------------------------
template<int LDQ>
__global__ __launch_bounds__(256) void scatter_kernel(const float* __restrict__ out,
                                                      const float* __restrict__ ev,
                                                      const int*   __restrict__ er,
                                                      const int*   __restrict__ ec,
                                                      float*       __restrict__ side,
                                                      int cin) {
    int tid = blockIdx.x * 256 + threadIdx.x;
    int e = tid >> LDQ;
    int q = tid & ((1 << LDQ) - 1);
    int r = er[e], c = ec[e];
    float v = ev[e];
    float4 xv = *(const float4*)(out + (size_t)c * OUT_D + cin + q * 4);
    float* dst = side + ((size_t)r << (LDQ + 2)) + q * 4;   // r * din + q*4
    atomicAdd(dst + 0, v * xv.x);
    atomicAdd(dst + 1, v * xv.y);
    atomicAdd(dst + 2, v * xv.z);
    atomicAdd(dst + 3, v * xv.w);
}

// ---------------------------------------------------------------------------
// Per node n:
//   a = x + side; b = x * side
//   h = leaky(a @ Wgc + bgc) + leaky(b @ Wbi + bbi)
//   x_next = h / max(||h||_2, 1e-12)   -> written to out columns [cout:cout+dout)
// One wave per node; lane = output dim. Weights staged in LDS.
// Grid must be exactly N_NODES/4 blocks (no guards; 150000 % 4 == 0).
// ---------------------------------------------------------------------------
__global__ __launch_bounds__(256) void dense_kernel(const float* __restrict__ side,
                                                    float*       __restrict__ out,
                                                    const float* __restrict__ Wgc,
                                                    const float* __restrict__ bgc,
                                                    const float* __restrict__ Wbi,
                                                    const float* __restrict__ bbi,
                                                    int din, int dout, int cin, int cout) {
    __shared__ float wg[64 * 64];
    __shared__ float wb[64 * 64];
    __shared__ float as[4][64];
    __shared__ float bs[4][64];

    int tid = threadIdx.x;
    int nw = din * dout;
    for (int i = tid; i < nw; i += 256) { wg[i] = Wgc[i]; wb[i] = Wbi[i]; }

    int w = tid >> 6, lane = tid & 63;
    int n = blockIdx.x * 4 + w;

    if (lane < din) {
        float xv = out[(size_t)n * OUT_D + cin + lane];
        float sv = side[(size_t)n * din + lane];
        as[w][lane] = xv + sv;
        bs[w][lane] = xv * sv;
    }
    __syncthreads();

    float h = 0.f;
    if (lane < dout) {
        float ag = bgc[lane], ab = bbi[lane];
        #pragma unroll 8
        for (int i = 0; i < din; ++i) {
            ag += as[w][i] * wg[i * dout + lane];
            ab += bs[w][i] * wb[i * dout + lane];
        }
        ag = ag > 0.f ? ag : 0.01f * ag;   // leaky_relu, slope 0.01
        ab = ab > 0.f ? ab : 0.01f * ab;
        h = ag + ab;
    }
    // L2 norm across the wave (inactive lanes contribute 0)
    float ss = h * h;
    #pragma unroll
    for (int off = 32; off; off >>= 1) ss += __shfl_xor(ss, off);

    if (lane < dout) {
        float inv = 1.f / fmaxf(sqrtf(ss), 1e-12f);
        out[(size_t)n * OUT_D + cout + lane] = h * inv;
    }
}

extern "C" void kernel_launch(void* const* d_in, const int* in_sizes, int n_in,
                              void* d_out, int out_size, void* d_ws, size_t ws_size,
                              hipStream_t stream) {
    const float* ue = (const float*)d_in[0];
    const float* ee = (const float*)d_in[1];
    const float* ev = (const float*)d_in[2];
    const int*   er = (const int*)d_in[3];
    const int*   ec = (const int*)d_in[4];
    float* out  = (float*)d_out;
    float* side = (float*)d_ws;   // up to N_NODES*64 floats = 38.4 MB

    // initial embeddings -> out[:, 0:64)
    init_x_kernel<<<(N_NODES * 16) / 256, 256, 0, stream>>>(ue, ee, out);

    // ---- layer 0: din=64 dout=64, x at col 0, write col 64 ----
    hipMemsetAsync(side, 0, (size_t)N_NODES * 64 * sizeof(float), stream);
    scatter_kernel<4><<<(N_EDGES * 16) / 256, 256, 0, stream>>>(out, ev, er, ec, side, 0);
    dense_kernel<<<N_NODES / 4, 256, 0, stream>>>(side, out,
        (const float*)d_in[5], (const float*)d_in[6],
        (const float*)d_in[7], (const float*)d_in[8], 64, 64, 0, 64);

    // ---- layer 1: din=64 dout=32, x at col 64, write col 128 ----
    hipMemsetAsync(side, 0, (size_t)N_NODES * 64 * sizeof(float), stream);
    scatter_kernel<4><<<(N_EDGES * 16) / 256, 256, 0, stream>>>(out, ev, er, ec, side, 64);
    dense_kernel<<<N_NODES / 4, 256, 0, stream>>>(side, out,
        (const float*)d_in[9], (const float*)d_in[10],
        (const float*)d_in[11], (const float*)d_in[12], 64, 32, 64, 128);

    // ---- layer 2: din=32 dout=16, x at col 128, write col 160 ----
    hipMemsetAsync(side, 0, (size_t)N_NODES * 32 * sizeof(float), stream);
    scatter_kernel<3><<<(N_EDGES * 8) / 256, 256, 0, stream>>>(out, ev, er, ec, side, 128);
    dense_kernel<<<N_NODES / 4, 256, 0, stream>>>(side, out,
        (const float*)d_in[13], (const float*)d_in[14],
        (const float*)d_in[15], (const float*)d_in[16], 32, 16, 128, 160);
}

// Round 2
// 1749.861 us; speedup vs baseline: 3.1199x; 3.1199x over previous
//
#include <hip/hip_runtime.h>

constexpr int N_USERS = 50000;
constexpr int N_ENT   = 100000;
constexpr int N_NODES = N_USERS + N_ENT;   // 150000
constexpr int N_EDGES = 2400000;
constexpr int OUT_D   = 176;               // 64 + 64 + 32 + 16

// ---------------------------------------------------------------------------
// Write initial x (concat of user/entity embeddings) into out columns [0:64)
// ---------------------------------------------------------------------------
__global__ __launch_bounds__(256) void init_x_kernel(const float* __restrict__ ue,
                                                     const float* __restrict__ ee,
                                                     float* __restrict__ out) {
    int tid = blockIdx.x * 256 + threadIdx.x;    // over N_NODES * 16 float4s
    int n = tid >> 4, q = tid & 15;
    const float* src = (n < N_USERS) ? ue + (size_t)n * 64
                                     : ee + (size_t)(n - N_USERS) * 64;
    float4 v = *(const float4*)(src + q * 4);
    *(float4*)(out + (size_t)n * OUT_D + q * 4) = v;
}

// ---------------------------------------------------------------------------
// CSR construction: histogram -> exclusive scan -> counting-sort scatter
// ---------------------------------------------------------------------------
__global__ __launch_bounds__(256) void hist_kernel(const int* __restrict__ er,
                                                   int* __restrict__ cnt) {
    int e = blockIdx.x * 256 + threadIdx.x;      // N_EDGES % 256 == 0
    atomicAdd(&cnt[er[e]], 1);
}

// Single-block exclusive scan over 150000 counts.
// In:  cursor[] = counts.  Out: start[0..N_NODES] = exclusive scan (+total),
//                               cursor[] = copy of start (running cursors).
__global__ __launch_bounds__(1024) void scan_kernel(int* __restrict__ cursor,
                                                    int* __restrict__ start) {
    __shared__ int wtot[16];
    __shared__ int carry_s;
    int tid = threadIdx.x;
    int lane = tid & 63, w = tid >> 6;
    if (tid == 0) carry_s = 0;
    __syncthreads();
    for (int base = 0; base < N_NODES; base += 1024) {
        int i = base + tid;
        int v = (i < N_NODES) ? cursor[i] : 0;
        int incl = v;
        #pragma unroll
        for (int off = 1; off < 64; off <<= 1) {
            int t = __shfl_up(incl, off);
            if (lane >= off) incl += t;
        }
        if (lane == 63) wtot[w] = incl;
        __syncthreads();
        int woff = 0, total = 0;
        #pragma unroll
        for (int k = 0; k < 16; ++k) {
            int tk = wtot[k];
            if (k < w) woff += tk;
            total += tk;
        }
        int ex = carry_s + woff + incl - v;
        if (i < N_NODES) { start[i] = ex; cursor[i] = ex; }
        __syncthreads();
        if (tid == 0) carry_s += total;
        __syncthreads();
    }
    if (tid == 0) start[N_NODES] = carry_s;
}

__global__ __launch_bounds__(256) void build_csr_kernel(const float* __restrict__ ev,
                                                        const int*   __restrict__ er,
                                                        const int*   __restrict__ ec,
                                                        int*  __restrict__ cursor,
                                                        int2* __restrict__ edges) {
    int e = blockIdx.x * 256 + threadIdx.x;      // N_EDGES % 256 == 0
    int r = er[e];
    int pos = atomicAdd(&cursor[r], 1);
    int2 p;
    p.x = ec[e];
    p.y = __float_as_int(ev[e]);
    edges[pos] = p;
}

// ---------------------------------------------------------------------------
// Fused per-layer kernel. One wave per node n:
//   side = sum_{e in row n} val_e * x[col_e]      (register accumulation)
//   a = x + side; b = x * side
//   h = leaky(a @ Wgc + bgc) + leaky(b @ Wbi + bbi)
//   out[n, cout:cout+DOUT) = h / max(||h||, 1e-12)
// 4 waves / 256-thread block; weights staged in LDS.
// Grid must be exactly N_NODES/4 (150000 % 4 == 0).
// ---------------------------------------------------------------------------
template<int DIN, int DOUT>
__global__ __launch_bounds__(256) void fused_layer_kernel(const int*  __restrict__ start,
                                                          const int2* __restrict__ edges,
                                                          float* __restrict__ out,
                                                          const float* __restrict__ Wgc,
                                                          const float* __restrict__ bgc,
                                                          const float* __restrict__ Wbi,
                                                          const float* __restrict__ bbi,
                                                          int cin, int cout) {
    __shared__ float wg[DIN * DOUT];
    __shared__ float wb[DIN * DOUT];
    __shared__ float as[4][DIN];
    __shared__ float bs[4][DIN];

    int tid = threadIdx.x;
    for (int i = tid; i < DIN * DOUT; i += 256) { wg[i] = Wgc[i]; wb[i] = Wbi[i]; }

    int w = tid >> 6, lane = tid & 63;
    int n = blockIdx.x * 4 + w;

    constexpr int NS = 64 / DIN;        // edge slots per wave (1 or 2)
    int slot = lane / DIN;
    int d = lane % DIN;

    int s = start[n], e_end = start[n + 1];
    float acc = 0.f;
    const float* xcol = out + cin + d;
    for (int e = s + slot; e < e_end; e += NS) {
        int2 p = edges[e];
        acc += __int_as_float(p.y) * xcol[(size_t)p.x * OUT_D];
    }
    // fold edge slots (no-op for DIN=64)
    #pragma unroll
    for (int m = 32; m >= DIN; m >>= 1) acc += __shfl_xor(acc, m);

    float xv = out[(size_t)n * OUT_D + cin + d];
    if (lane < DIN) { as[w][lane] = xv + acc; bs[w][lane] = xv * acc; }
    __syncthreads();

    float h = 0.f;
    if (lane < DOUT) {
        float ag = bgc[lane], ab = bbi[lane];
        #pragma unroll
        for (int i = 0; i < DIN; ++i) {
            ag += as[w][i] * wg[i * DOUT + lane];
            ab += bs[w][i] * wb[i * DOUT + lane];
        }
        ag = ag > 0.f ? ag : 0.01f * ag;   // leaky_relu slope 0.01
        ab = ab > 0.f ? ab : 0.01f * ab;
        h = ag + ab;
    }
    float ss = h * h;
    #pragma unroll
    for (int off = 32; off; off >>= 1) ss += __shfl_xor(ss, off);

    if (lane < DOUT) {
        float inv = 1.f / fmaxf(sqrtf(ss), 1e-12f);
        out[(size_t)n * OUT_D + cout + lane] = h * inv;
    }
}

extern "C" void kernel_launch(void* const* d_in, const int* in_sizes, int n_in,
                              void* d_out, int out_size, void* d_ws, size_t ws_size,
                              hipStream_t stream) {
    const float* ue = (const float*)d_in[0];
    const float* ee = (const float*)d_in[1];
    const float* ev = (const float*)d_in[2];
    const int*   er = (const int*)d_in[3];
    const int*   ec = (const int*)d_in[4];
    float* out = (float*)d_out;

    // workspace layout (4-byte units): cursor[150000], start[150001] (padded
    // to 150016), edges[2.4M int2] at 8B-aligned offset. Total ~20.4 MB.
    int*  cursor = (int*)d_ws;
    int*  startp = cursor + 150016;
    int2* edges  = (int2*)((char*)d_ws + (size_t)300544 * 4);

    init_x_kernel<<<(N_NODES * 16) / 256, 256, 0, stream>>>(ue, ee, out);

    hipMemsetAsync(cursor, 0, (size_t)N_NODES * sizeof(int), stream);
    hist_kernel<<<N_EDGES / 256, 256, 0, stream>>>(er, cursor);
    scan_kernel<<<1, 1024, 0, stream>>>(cursor, startp);
    build_csr_kernel<<<N_EDGES / 256, 256, 0, stream>>>(ev, er, ec, cursor, edges);

    fused_layer_kernel<64, 64><<<N_NODES / 4, 256, 0, stream>>>(startp, edges, out,
        (const float*)d_in[5], (const float*)d_in[6],
        (const float*)d_in[7], (const float*)d_in[8], 0, 64);
    fused_layer_kernel<64, 32><<<N_NODES / 4, 256, 0, stream>>>(startp, edges, out,
        (const float*)d_in[9], (const float*)d_in[10],
        (const float*)d_in[11], (const float*)d_in[12], 64, 128);
    fused_layer_kernel<32, 16><<<N_NODES / 4, 256, 0, stream>>>(startp, edges, out,
        (const float*)d_in[13], (const float*)d_in[14],
        (const float*)d_in[15], (const float*)d_in[16], 128, 160);
}

// Round 3
// 1138.202 us; speedup vs baseline: 4.7965x; 1.5374x over previous
//
#include <hip/hip_runtime.h>

constexpr int N_USERS = 50000;
constexpr int N_ENT   = 100000;
constexpr int N_NODES = N_USERS + N_ENT;   // 150000
constexpr int N_EDGES = 2400000;
constexpr int OUT_D   = 176;               // 64 + 64 + 32 + 16

// ---------------------------------------------------------------------------
// Write initial x (concat of user/entity embeddings) into out columns [0:64)
// ---------------------------------------------------------------------------
__global__ __launch_bounds__(256) void init_x_kernel(const float* __restrict__ ue,
                                                     const float* __restrict__ ee,
                                                     float* __restrict__ out) {
    int tid = blockIdx.x * 256 + threadIdx.x;    // over N_NODES * 16 float4s
    int n = tid >> 4, q = tid & 15;
    const float* src = (n < N_USERS) ? ue + (size_t)n * 64
                                     : ee + (size_t)(n - N_USERS) * 64;
    float4 v = *(const float4*)(src + q * 4);
    *(float4*)(out + (size_t)n * OUT_D + q * 4) = v;
}

// ---------------------------------------------------------------------------
// CSR construction: histogram -> exclusive scan -> counting-sort scatter
// ---------------------------------------------------------------------------
__global__ __launch_bounds__(256) void hist_kernel(const int* __restrict__ er,
                                                   int* __restrict__ cnt) {
    int e = blockIdx.x * 256 + threadIdx.x;      // N_EDGES % 256 == 0
    atomicAdd(&cnt[er[e]], 1);
}

// Single-block exclusive scan over 150000 counts.
__global__ __launch_bounds__(1024) void scan_kernel(int* __restrict__ cursor,
                                                    int* __restrict__ start) {
    __shared__ int wtot[16];
    __shared__ int carry_s;
    int tid = threadIdx.x;
    int lane = tid & 63, w = tid >> 6;
    if (tid == 0) carry_s = 0;
    __syncthreads();
    for (int base = 0; base < N_NODES; base += 1024) {
        int i = base + tid;
        int v = (i < N_NODES) ? cursor[i] : 0;
        int incl = v;
        #pragma unroll
        for (int off = 1; off < 64; off <<= 1) {
            int t = __shfl_up(incl, off);
            if (lane >= off) incl += t;
        }
        if (lane == 63) wtot[w] = incl;
        __syncthreads();
        int woff = 0, total = 0;
        #pragma unroll
        for (int k = 0; k < 16; ++k) {
            int tk = wtot[k];
            if (k < w) woff += tk;
            total += tk;
        }
        int ex = carry_s + woff + incl - v;
        if (i < N_NODES) { start[i] = ex; cursor[i] = ex; }
        __syncthreads();
        if (tid == 0) carry_s += total;
        __syncthreads();
    }
    if (tid == 0) start[N_NODES] = carry_s;
}

__global__ __launch_bounds__(256) void build_csr_kernel(const float* __restrict__ ev,
                                                        const int*   __restrict__ er,
                                                        const int*   __restrict__ ec,
                                                        int*  __restrict__ cursor,
                                                        int2* __restrict__ edges) {
    int e = blockIdx.x * 256 + threadIdx.x;      // N_EDGES % 256 == 0
    int r = er[e];
    int pos = atomicAdd(&cursor[r], 1);
    int2 p;
    p.x = ec[e];
    p.y = __float_as_int(ev[e]);
    edges[pos] = p;
}

// ---------------------------------------------------------------------------
// Fused per-layer kernel. One wave per node n:
//   side = sum_{e in row n} val_e * x[col_e]      (register accumulation,
//                                                  4-deep pipelined gather)
//   a = x + side; b = x * side
//   h = leaky(a @ Wgc + bgc) + leaky(b @ Wbi + bbi)
//   out[n, cout:cout+DOUT) = h / max(||h||, 1e-12)
// Weights read directly from global (L1-hot, 32 KB total) — no LDS staging,
// so occupancy is wave-limited, not LDS-limited.
// ---------------------------------------------------------------------------
template<int DIN, int DOUT>
__global__ __launch_bounds__(256, 8) void fused_layer_kernel(const int*  __restrict__ start,
                                                             const int2* __restrict__ edges,
                                                             float* __restrict__ out,
                                                             const float* __restrict__ Wgc,
                                                             const float* __restrict__ bgc,
                                                             const float* __restrict__ Wbi,
                                                             const float* __restrict__ bbi,
                                                             int cin, int cout) {
    __shared__ float as[4][DIN];
    __shared__ float bs[4][DIN];

    int tid = threadIdx.x;
    int w = tid >> 6, lane = tid & 63;
    int n = blockIdx.x * 4 + w;

    constexpr int NS = 64 / DIN;        // edge slots per wave (1 or 2)
    int slot = (NS > 1) ? (lane >> 5) & (NS - 1) : 0;  // lane/DIN for DIN=32
    int d = lane & (DIN - 1);

    int s = start[n], e_end = start[n + 1];
    float acc = 0.f;
    const float* xcol = out + cin + d;

    int e = s + slot;
    // 4-deep software pipeline: 4 independent edge loads, then 4 independent
    // gathers -> ~4x latency hiding vs the serial chain.
    for (; e + 3 * NS < e_end; e += 4 * NS) {
        int2 p0 = edges[e];
        int2 p1 = edges[e + NS];
        int2 p2 = edges[e + 2 * NS];
        int2 p3 = edges[e + 3 * NS];
        float x0 = xcol[(size_t)p0.x * OUT_D];
        float x1 = xcol[(size_t)p1.x * OUT_D];
        float x2 = xcol[(size_t)p2.x * OUT_D];
        float x3 = xcol[(size_t)p3.x * OUT_D];
        acc += __int_as_float(p0.y) * x0;
        acc += __int_as_float(p1.y) * x1;
        acc += __int_as_float(p2.y) * x2;
        acc += __int_as_float(p3.y) * x3;
    }
    for (; e < e_end; e += NS) {
        int2 p = edges[e];
        acc += __int_as_float(p.y) * xcol[(size_t)p.x * OUT_D];
    }
    // fold edge slots (no-op for DIN=64)
    if (NS > 1) acc += __shfl_xor(acc, 32);

    float xv = out[(size_t)n * OUT_D + cin + d];
    if (lane < DIN) { as[w][lane] = xv + acc; bs[w][lane] = xv * acc; }
    __syncthreads();

    float h = 0.f;
    if (lane < DOUT) {
        float ag = bgc[lane], ab = bbi[lane];
        #pragma unroll 16
        for (int i = 0; i < DIN; ++i) {
            ag += as[w][i] * Wgc[i * DOUT + lane];
            ab += bs[w][i] * Wbi[i * DOUT + lane];
        }
        ag = ag > 0.f ? ag : 0.01f * ag;   // leaky_relu slope 0.01
        ab = ab > 0.f ? ab : 0.01f * ab;
        h = ag + ab;
    }
    float ss = h * h;
    #pragma unroll
    for (int off = 32; off; off >>= 1) ss += __shfl_xor(ss, off);

    if (lane < DOUT) {
        float inv = 1.f / fmaxf(sqrtf(ss), 1e-12f);
        out[(size_t)n * OUT_D + cout + lane] = h * inv;
    }
}

extern "C" void kernel_launch(void* const* d_in, const int* in_sizes, int n_in,
                              void* d_out, int out_size, void* d_ws, size_t ws_size,
                              hipStream_t stream) {
    const float* ue = (const float*)d_in[0];
    const float* ee = (const float*)d_in[1];
    const float* ev = (const float*)d_in[2];
    const int*   er = (const int*)d_in[3];
    const int*   ec = (const int*)d_in[4];
    float* out = (float*)d_out;

    // workspace layout (4-byte units): cursor[150000] (pad 150016),
    // start[150001] (pad 150528 -> 8B-aligned), edges[2.4M int2].
    int*  cursor = (int*)d_ws;
    int*  startp = cursor + 150016;
    int2* edges  = (int2*)((char*)d_ws + (size_t)300544 * 4);

    init_x_kernel<<<(N_NODES * 16) / 256, 256, 0, stream>>>(ue, ee, out);

    hipMemsetAsync(cursor, 0, (size_t)N_NODES * sizeof(int), stream);
    hist_kernel<<<N_EDGES / 256, 256, 0, stream>>>(er, cursor);
    scan_kernel<<<1, 1024, 0, stream>>>(cursor, startp);
    build_csr_kernel<<<N_EDGES / 256, 256, 0, stream>>>(ev, er, ec, cursor, edges);

    fused_layer_kernel<64, 64><<<N_NODES / 4, 256, 0, stream>>>(startp, edges, out,
        (const float*)d_in[5], (const float*)d_in[6],
        (const float*)d_in[7], (const float*)d_in[8], 0, 64);
    fused_layer_kernel<64, 32><<<N_NODES / 4, 256, 0, stream>>>(startp, edges, out,
        (const float*)d_in[9], (const float*)d_in[10],
        (const float*)d_in[11], (const float*)d_in[12], 64, 128);
    fused_layer_kernel<32, 16><<<N_NODES / 4, 256, 0, stream>>>(startp, edges, out,
        (const float*)d_in[13], (const float*)d_in[14],
        (const float*)d_in[15], (const float*)d_in[16], 128, 160);
}